// Round 1
// baseline (43.180 us; speedup 1.0000x reference)
//
#include <hip/hip_runtime.h>
#include <float.h>
#include <math.h>

namespace {

constexpr int kB  = 16;
constexpr int kC  = 64;
constexpr int kH  = 224;
constexpr int kW  = 224;
constexpr int kOH = 112;
constexpr int kOW = 112;
constexpr int kOW2 = kOW / 2;                       // 56 output-pairs per row
constexpr int kTotalThreads = kB * kC * kOH * kOW2; // 6,422,528

__device__ __forceinline__ float fast_rcp(float x) {
  // v_rcp_f32: ~1 ulp approx, plenty within the 1e-1 absmax threshold.
  return __builtin_amdgcn_rcpf(x);
}

// One 2x2 window: taps a,b,c,d (row0: a,b; row1: c,d), blend weight beta.
__device__ __forceinline__ float window(float a, float b, float c, float d,
                                        float beta) {
  // --- EDSCW ---
  float avg  = (a + b + c + d) * 0.25f;
  float avg2 = avg * avg;
  float ta   = 2.0f * avg;
  float da = (ta * a) * fast_rcp(fmaf(a, a, avg2));
  float db = (ta * b) * fast_rcp(fmaf(b, b, avg2));
  float dc = (ta * c) * fast_rcp(fmaf(c, c, avg2));
  float dd = (ta * d) * fast_rcp(fmaf(d, d, avg2));
  float md = fmaxf(fmaxf(da, db), fmaxf(dc, dd));
  float ea = __expf(da - md);
  float eb = __expf(db - md);
  float ec = __expf(dc - md);
  float ed = __expf(dd - md);
  float edscw = (ea * a + eb * b + ec * c + ed * d) *
                fast_rcp(ea + eb + ec + ed);
  // --- EM (SoftPool) ---
  float mx = fmaxf(fmaxf(a, b), fmaxf(c, d));
  float fa = __expf(a - mx);
  float fb = __expf(b - mx);
  float fc = __expf(c - mx);
  float fd = __expf(d - mx);
  float em = (fa * a + fb * b + fc * c + fd * d) *
             fast_rcp(fa + fb + fc + fd);
  // --- blend + nan_to_num ---
  float r = beta * edscw + (1.0f - beta) * em;
  if (isnan(r))      r = 0.0f;
  else if (isinf(r)) r = (r > 0.0f) ? FLT_MAX : -FLT_MAX;
  return r;
}

__global__ void __launch_bounds__(256)
adapool2d_kernel(const float* __restrict__ x,
                 const float* __restrict__ beta,
                 float* __restrict__ out) {
  int tid = blockIdx.x * blockDim.x + threadIdx.x;
  if (tid >= kTotalThreads) return;

  int ow2 = tid % kOW2;          // which pair of output columns
  int t   = tid / kOW2;
  int oh  = t % kOH;
  int bc  = t / kOH;             // fused batch*channel

  // Input window rows: 2*oh and 2*oh+1, columns 4*ow2 .. 4*ow2+3
  const float* rowp = x + (size_t)bc * (kH * kW)
                        + (size_t)(2 * oh) * kW
                        + 4 * ow2;
  float4 r0 = *reinterpret_cast<const float4*>(rowp);
  float4 r1 = *reinterpret_cast<const float4*>(rowp + kW);

  // beta[oh][2*ow2 .. 2*ow2+1] — 8B-aligned (even float offset)
  float2 bt = *reinterpret_cast<const float2*>(beta + oh * kOW + 2 * ow2);

  float o0 = window(r0.x, r0.y, r1.x, r1.y, bt.x);
  float o1 = window(r0.z, r0.w, r1.z, r1.w, bt.y);

  float2 o = make_float2(o0, o1);
  *reinterpret_cast<float2*>(out + (size_t)bc * (kOH * kOW)
                                 + (size_t)oh * kOW + 2 * ow2) = o;
}

}  // namespace

extern "C" void kernel_launch(void* const* d_in, const int* in_sizes, int n_in,
                              void* d_out, int out_size, void* d_ws, size_t ws_size,
                              hipStream_t stream) {
  const float* x    = (const float*)d_in[0];
  const float* beta = (const float*)d_in[1];
  float* out        = (float*)d_out;

  constexpr int threads = 256;
  constexpr int blocks  = (kTotalThreads + threads - 1) / threads;
  adapool2d_kernel<<<blocks, threads, 0, stream>>>(x, beta, out);
}